// Round 5
// baseline (3135.869 us; speedup 1.0000x reference)
//
#include <hip/hip_runtime.h>

#define BSZ 256
#define NND 22
#define BN_EPS 1e-5f

// ---------------------------------------------------------------------------
// Shared conv core: each thread computes 4 consecutive conv1d(k=7,pad=3)
// outputs (positions t0+4*tid .. +3) from LDS-staged input and LDS-staged
// weights (layout [c][k][o], float4-broadcast reads).
// s_in[c][i] = x[t0 + i - 3] (zero-padded OOB), SROW = TILE+8 (16B aligned).
// ---------------------------------------------------------------------------
template<int CIN, int COUT, int SROW>
__device__ __forceinline__ void conv_core4(
    const float (*s_in)[SROW], const float* s_w, int tid, float y[COUT][4]) {
#pragma unroll
  for (int o = 0; o < COUT; o++)
#pragma unroll
    for (int r = 0; r < 4; r++) y[o][r] = 0.f;
#pragma unroll
  for (int c = 0; c < CIN; c++) {
    float xr[10];
    const float4* xp = (const float4*)&s_in[c][4 * tid];
    float4 xa = xp[0], xb = xp[1];
    xr[0] = xa.x; xr[1] = xa.y; xr[2] = xa.z; xr[3] = xa.w;
    xr[4] = xb.x; xr[5] = xb.y; xr[6] = xb.z; xr[7] = xb.w;
    xr[8] = s_in[c][4 * tid + 8]; xr[9] = s_in[c][4 * tid + 9];
#pragma unroll
    for (int k = 0; k < 7; k++) {
      const float4* wp = (const float4*)&s_w[(c * 7 + k) * COUT];
#pragma unroll
      for (int o4 = 0; o4 < COUT / 4; o4++) {
        float4 wv = wp[o4];
#pragma unroll
        for (int r = 0; r < 4; r++) {
          y[4 * o4 + 0][r] += wv.x * xr[r + k];
          y[4 * o4 + 1][r] += wv.y * xr[r + k];
          y[4 * o4 + 2][r] += wv.z * xr[r + k];
          y[4 * o4 + 3][r] += wv.w * xr[r + k];
        }
      }
    }
  }
}

template<int CIN, int COUT, int NTH>
__device__ __forceinline__ void stage_weights(const float* __restrict__ w,
                                              float* s_w, int tid) {
  for (int i = tid; i < CIN * 7 * COUT; i += NTH) {
    int c = i / (7 * COUT), k = (i / COUT) % 7, o = i % COUT;
    s_w[i] = w[(o * CIN + c) * 7 + k];
  }
}

// ---------------------------------------------------------------------------
// Stats pass: conv + per-channel sum/sum^2 over tile -> private partial slot.
// grid: (NT, B, N), block NTH. TILE = 4*NTH conv positions.
// part slot = ((n*NT + tile)*BSZ + b), 2*COUT floats.
// ---------------------------------------------------------------------------
template<int CIN, int COUT, int LIN, int NTH, int NT>
__global__ __launch_bounds__(NTH) void conv_stats4(
    const float* __restrict__ in, long sn, long sb, long sc,
    const float* __restrict__ w, float* __restrict__ part) {
  const int TILE = 4 * NTH;
  const int SROW = TILE + 8;
  __shared__ alignas(16) float s_in[CIN][SROW];
  __shared__ alignas(16) float s_w[CIN * 7 * COUT];
  __shared__ float s_red[2][NTH / 64][COUT];
  int tid = threadIdx.x, n = blockIdx.z, b = blockIdx.y;
  int t0 = blockIdx.x * TILE;
  const float* base = in + (long)n * sn + (long)b * sb;
  stage_weights<CIN, COUT, NTH>(w, s_w, tid);
  for (int c = 0; c < CIN; c++)
    for (int i = tid; i < TILE + 6; i += NTH) {
      int l = t0 + i - 3;
      s_in[c][i] = (l >= 0 && l < LIN) ? base[(long)c * sc + l] : 0.f;
    }
  __syncthreads();
  float y[COUT][4];
  conv_core4<CIN, COUT, SROW>(s_in, s_w, tid, y);
  bool valid = (t0 + 4 * tid) < LIN;  // LIN % 4 == 0: all-or-nothing
  int lane = tid & 63, wv = tid >> 6;
#pragma unroll
  for (int o = 0; o < COUT; o++) {
    float s = 0.f, q = 0.f;
    if (valid) {
#pragma unroll
      for (int r = 0; r < 4; r++) { s += y[o][r]; q += y[o][r] * y[o][r]; }
    }
#pragma unroll
    for (int off = 32; off > 0; off >>= 1) {
      s += __shfl_down(s, off, 64);
      q += __shfl_down(q, off, 64);
    }
    if (lane == 0) { s_red[0][wv][o] = s; s_red[1][wv][o] = q; }
  }
  __syncthreads();
  if (tid < COUT) {
    float s = 0.f, q = 0.f;
#pragma unroll
    for (int g = 0; g < NTH / 64; g++) { s += s_red[0][g][tid]; q += s_red[1][g][tid]; }
    long slot = ((long)n * NT + blockIdx.x) * BSZ + b;
    part[slot * (2 * COUT) + tid] = s;
    part[slot * (2 * COUT) + COUT + tid] = q;
  }
}

// ---------------------------------------------------------------------------
// Reduce partials -> BN scale/shift per (node, channel).
// scs layout: scs[n*64 + o] = scale, scs[n*64 + 32 + o] = shift
// ---------------------------------------------------------------------------
template<int C, int NSLOT, int LIN>
__global__ __launch_bounds__(256) void stats_reduce(
    const float* __restrict__ part,
    const float* __restrict__ gamma, const float* __restrict__ beta,
    float* __restrict__ scs) {
  const int V = 2 * C;
  const int GRP = 256 / V;
  int n = blockIdx.x, tid = threadIdx.x;
  int j = tid % V, g = tid / V;
  const float* p = part + (long)n * NSLOT * V;
  float s = 0.f;
  for (int sl = g; sl < NSLOT; sl += GRP) s += p[(long)sl * V + j];
  __shared__ float red[V][GRP];
  __shared__ float tot[V];
  red[j][g] = s;
  __syncthreads();
  if (tid < V) {
    float t = 0.f;
#pragma unroll
    for (int gg = 0; gg < GRP; gg++) t += red[tid][gg];
    tot[tid] = t;
  }
  __syncthreads();
  if (tid < C) {
    float cnt = (float)BSZ * (float)LIN;
    float m = tot[tid] / cnt;
    float var = tot[C + tid] / cnt - m * m;
    float istd = 1.0f / sqrtf(var + BN_EPS);
    float scl = gamma[tid] * istd;
    scs[n * 64 + tid] = scl;
    scs[n * 64 + 32 + tid] = beta[tid] - m * scl;
  }
}

// ---------------------------------------------------------------------------
// Apply pass: conv + BN(scale/shift) + ReLU + MaxPool(2) -> h.
// Thread computes 4 conv positions -> 2 pooled, stored as float2.
// grid: (NT, B, N), block NTH. outh layout [n][b][COUT][LP]
// ---------------------------------------------------------------------------
template<int CIN, int COUT, int LIN, int NTH>
__global__ __launch_bounds__(NTH) void conv_bn_pool4(
    const float* __restrict__ in, long sn, long sb, long sc,
    const float* __restrict__ w, const float* __restrict__ scs,
    float* __restrict__ outh) {
  const int LP = LIN / 2;
  const int TILE = 4 * NTH;
  const int SROW = TILE + 8;
  __shared__ alignas(16) float s_in[CIN][SROW];
  __shared__ alignas(16) float s_w[CIN * 7 * COUT];
  __shared__ float s_scale[COUT], s_shift[COUT];
  int tid = threadIdx.x, n = blockIdx.z, b = blockIdx.y;
  int P0 = blockIdx.x * (2 * NTH);
  int t0 = 2 * P0;
  const float* base = in + (long)n * sn + (long)b * sb;
  if (tid < COUT) {
    s_scale[tid] = scs[n * 64 + tid];
    s_shift[tid] = scs[n * 64 + 32 + tid];
  }
  stage_weights<CIN, COUT, NTH>(w, s_w, tid);
  for (int c = 0; c < CIN; c++)
    for (int i = tid; i < TILE + 6; i += NTH) {
      int l = t0 + i - 3;
      s_in[c][i] = (l >= 0 && l < LIN) ? base[(long)c * sc + l] : 0.f;
    }
  __syncthreads();
  float y[COUT][4];
  conv_core4<CIN, COUT, SROW>(s_in, s_w, tid, y);
  int pl = P0 + 2 * tid;
  if (pl >= LP) return;  // LP % 2 == 0: all-or-nothing
  long obase = ((long)n * BSZ + b) * COUT * (long)LP;
#pragma unroll
  for (int o = 0; o < COUT; o++) {
    float a0 = y[o][0] * s_scale[o] + s_shift[o];
    float a1 = y[o][1] * s_scale[o] + s_shift[o];
    float a2 = y[o][2] * s_scale[o] + s_shift[o];
    float a3 = y[o][3] * s_scale[o] + s_shift[o];
    float2 v;
    v.x = fmaxf(fmaxf(a0, a1), 0.f);
    v.y = fmaxf(fmaxf(a2, a3), 0.f);
    *(float2*)&outh[obase + (long)o * LP + pl] = v;
  }
}

// ---------------------------------------------------------------------------
// Block-3 apply fused with AdaptiveAvgPool(1) -> feat[b][n][16].
// grid: (1, B, N), block NTH (=128, covers all 250 pooled positions).
// ---------------------------------------------------------------------------
template<int CIN, int COUT, int LIN, int NTH>
__global__ __launch_bounds__(NTH) void conv_bn_pool_feat4(
    const float* __restrict__ in, long sn, long sb, long sc,
    const float* __restrict__ w, const float* __restrict__ scs,
    float* __restrict__ feat) {
  const int LP = LIN / 2;
  const int TILE = 4 * NTH;
  const int SROW = TILE + 8;
  __shared__ alignas(16) float s_in[CIN][SROW];
  __shared__ alignas(16) float s_w[CIN * 7 * COUT];
  __shared__ float s_scale[COUT], s_shift[COUT];
  __shared__ float s_red[NTH / 64][COUT];
  int tid = threadIdx.x, n = blockIdx.z, b = blockIdx.y;
  const float* base = in + (long)n * sn + (long)b * sb;
  if (tid < COUT) {
    s_scale[tid] = scs[n * 64 + tid];
    s_shift[tid] = scs[n * 64 + 32 + tid];
  }
  stage_weights<CIN, COUT, NTH>(w, s_w, tid);
  for (int c = 0; c < CIN; c++)
    for (int i = tid; i < TILE + 6; i += NTH) {
      int l = i - 3;
      s_in[c][i] = (l >= 0 && l < LIN) ? base[(long)c * sc + l] : 0.f;
    }
  __syncthreads();
  float y[COUT][4];
  conv_core4<CIN, COUT, SROW>(s_in, s_w, tid, y);
  bool valid = (2 * tid) < LP;  // LP = 250 = 2*125: all-or-nothing
  int lane = tid & 63, wv = tid >> 6;
#pragma unroll
  for (int o = 0; o < COUT; o++) {
    float s = 0.f;
    if (valid) {
      float a0 = y[o][0] * s_scale[o] + s_shift[o];
      float a1 = y[o][1] * s_scale[o] + s_shift[o];
      float a2 = y[o][2] * s_scale[o] + s_shift[o];
      float a3 = y[o][3] * s_scale[o] + s_shift[o];
      s = fmaxf(fmaxf(a0, a1), 0.f) + fmaxf(fmaxf(a2, a3), 0.f);
    }
#pragma unroll
    for (int off = 32; off > 0; off >>= 1) s += __shfl_down(s, off, 64);
    if (lane == 0) s_red[wv][o] = s;
  }
  __syncthreads();
  if (tid < COUT) {
    float s = 0.f;
#pragma unroll
    for (int g = 0; g < NTH / 64; g++) s += s_red[g][tid];
    feat[((long)b * NND + n) * COUT + tid] = s * (1.0f / (float)LP);
  }
}

// ---------------------------------------------------------------------------
// Graph tail: adjacency (top-4 incl self) + 3 GCN layers + node-mean + MLP head
// grid: (B), block: 256. One workgroup per batch element, all in LDS.
// ---------------------------------------------------------------------------
__global__ __launch_bounds__(256) void graph_head(
    const float* __restrict__ feat,
    const float* __restrict__ gw1, const float* __restrict__ gb1,
    const float* __restrict__ gw2, const float* __restrict__ gb2,
    const float* __restrict__ gw3, const float* __restrict__ gb3,
    const float* __restrict__ fw1, const float* __restrict__ fb1,
    const float* __restrict__ fw2, const float* __restrict__ fb2,
    float* __restrict__ out) {
  int b = blockIdx.x, tid = threadIdx.x;
  __shared__ float s_feat[NND][16];
  __shared__ float s_sq[NND];
  __shared__ float s_dist[NND][NND];
  __shared__ float s_adj[NND][NND];
  __shared__ float s_x[NND][128];
  __shared__ float s_t[NND][128];
  __shared__ float s_pool[128];
  __shared__ float s_h[64];
  for (int i = tid; i < NND * 16; i += 256) s_feat[i >> 4][i & 15] = feat[b * NND * 16 + i];
  __syncthreads();
  if (tid < NND) {
    float s = 0.f;
    for (int c = 0; c < 16; c++) s += s_feat[tid][c] * s_feat[tid][c];
    s_sq[tid] = s;
  }
  __syncthreads();
  for (int i = tid; i < NND * NND; i += 256) {
    int nn = i / NND, m = i % NND;
    float d = 0.f;
    for (int c = 0; c < 16; c++) d += s_feat[nn][c] * s_feat[m][c];
    s_dist[nn][m] = s_sq[nn] + s_sq[m] - 2.f * d;  // diagonal exactly 0
    s_adj[nn][m] = 0.f;
  }
  __syncthreads();
  if (tid < NND) {  // top-4 smallest per row, ties -> earliest index (matches top_k)
    unsigned used = 0;
    for (int j = 0; j < 4; j++) {
      float best = 3.4e38f; int bi = 0;
      for (int m = 0; m < NND; m++)
        if (!((used >> m) & 1u) && s_dist[tid][m] < best) { best = s_dist[tid][m]; bi = m; }
      used |= 1u << bi;
      s_adj[tid][bi] = 0.25f;
    }
  }
  __syncthreads();
  // ---- GCN layer 1: 16 -> 32 ----
  for (int i = tid; i < NND * 32; i += 256) {
    int nn = i / 32, f = i % 32;
    float a = 0.f;
    for (int c = 0; c < 16; c++) a += s_feat[nn][c] * gw1[c * 32 + f];
    s_t[nn][f] = a;
  }
  __syncthreads();
  for (int i = tid; i < NND * 32; i += 256) {
    int nn = i / 32, f = i % 32;
    float a = gb1[f];
    for (int m = 0; m < NND; m++) a += s_adj[nn][m] * s_t[m][f];
    s_x[nn][f] = fmaxf(a, 0.f);
  }
  __syncthreads();
  // ---- GCN layer 2: 32 -> 64 ----
  for (int i = tid; i < NND * 64; i += 256) {
    int nn = i / 64, f = i % 64;
    float a = 0.f;
    for (int c = 0; c < 32; c++) a += s_x[nn][c] * gw2[c * 64 + f];
    s_t[nn][f] = a;
  }
  __syncthreads();
  for (int i = tid; i < NND * 64; i += 256) {
    int nn = i / 64, f = i % 64;
    float a = gb2[f];
    for (int m = 0; m < NND; m++) a += s_adj[nn][m] * s_t[m][f];
    s_x[nn][f] = fmaxf(a, 0.f);
  }
  __syncthreads();
  // ---- GCN layer 3: 64 -> 128 ----
  for (int i = tid; i < NND * 128; i += 256) {
    int nn = i / 128, f = i % 128;
    float a = 0.f;
    for (int c = 0; c < 64; c++) a += s_x[nn][c] * gw3[c * 128 + f];
    s_t[nn][f] = a;
  }
  __syncthreads();
  for (int i = tid; i < NND * 128; i += 256) {
    int nn = i / 128, f = i % 128;
    float a = gb3[f];
    for (int m = 0; m < NND; m++) a += s_adj[nn][m] * s_t[m][f];
    s_x[nn][f] = fmaxf(a, 0.f);
  }
  __syncthreads();
  if (tid < 128) {
    float a = 0.f;
    for (int m = 0; m < NND; m++) a += s_x[m][tid];
    s_pool[tid] = a * (1.0f / (float)NND);
  }
  __syncthreads();
  if (tid < 64) {
    float a = fb1[tid];
    for (int c = 0; c < 128; c++) a += s_pool[c] * fw1[c * 64 + tid];
    s_h[tid] = a;
  }
  __syncthreads();
  if (tid < 4) {
    float a = fb2[tid];
    for (int c = 0; c < 64; c++) a += s_h[c] * fw2[c * 4 + tid];
    out[b * 4 + tid] = a;
  }
}

extern "C" void kernel_launch(void* const* d_in, const int* in_sizes, int n_in,
                              void* d_out, int out_size, void* d_ws, size_t ws_size,
                              hipStream_t stream) {
  (void)in_sizes; (void)n_in; (void)out_size; (void)ws_size;
  const float* x   = (const float*)d_in[0];
  const float* w1  = (const float*)d_in[1];
  const float* g1  = (const float*)d_in[2];
  const float* b1  = (const float*)d_in[3];
  const float* w2  = (const float*)d_in[4];
  const float* g2  = (const float*)d_in[5];
  const float* b2  = (const float*)d_in[6];
  const float* w3  = (const float*)d_in[7];
  const float* g3  = (const float*)d_in[8];
  const float* b3  = (const float*)d_in[9];
  const float* gw1 = (const float*)d_in[10];
  const float* gb1 = (const float*)d_in[11];
  const float* gw2 = (const float*)d_in[12];
  const float* gb2 = (const float*)d_in[13];
  const float* gw3 = (const float*)d_in[14];
  const float* gb3 = (const float*)d_in[15];
  const float* fw1 = (const float*)d_in[16];
  const float* fb1 = (const float*)d_in[17];
  const float* fw2 = (const float*)d_in[18];
  const float* fb2 = (const float*)d_in[19];

  float* ws = (float*)d_ws;
  const long H1 = (long)NND * BSZ * 4 * 1000;  // 22,528,000 floats
  const long H2 = (long)NND * BSZ * 8 * 500;   // 22,528,000 floats
  float* h1   = ws;
  float* h2   = h1 + H1;
  float* feat = h2 + H2;                        // B*N*16 = 90,112
  float* scs1 = feat + (long)BSZ * NND * 16;    // scale/shift, 22*64 each
  float* scs2 = scs1 + NND * 64;
  float* scs3 = scs2 + NND * 64;
  float* p1   = scs3 + NND * 64;                // 22*512 slots * 8
  float* p2   = p1 + (long)NND * 512 * 8;       // 22*256 slots * 16
  float* p3   = p2 + (long)NND * 256 * 16;      // 22*256 slots * 32

  // block 1: input x is (B, N, T): node stride T, batch stride N*T
  conv_stats4<1, 4, 2000, 256, 2><<<dim3(2, BSZ, NND), dim3(256), 0, stream>>>(
      x, 2000, (long)NND * 2000, 0, w1, p1);
  stats_reduce<4, 512, 2000><<<dim3(NND), dim3(256), 0, stream>>>(p1, g1, b1, scs1);
  conv_bn_pool4<1, 4, 2000, 256><<<dim3(2, BSZ, NND), dim3(256), 0, stream>>>(
      x, 2000, (long)NND * 2000, 0, w1, scs1, h1);
  // block 2: h1 layout [n][b][4][1000]
  conv_stats4<4, 8, 1000, 256, 1><<<dim3(1, BSZ, NND), dim3(256), 0, stream>>>(
      h1, (long)BSZ * 4000, 4000, 1000, w2, p2);
  stats_reduce<8, 256, 1000><<<dim3(NND), dim3(256), 0, stream>>>(p2, g2, b2, scs2);
  conv_bn_pool4<4, 8, 1000, 256><<<dim3(1, BSZ, NND), dim3(256), 0, stream>>>(
      h1, (long)BSZ * 4000, 4000, 1000, w2, scs2, h2);
  // block 3: h2 layout [n][b][8][500]; apply fused with avg-pool -> feat
  conv_stats4<8, 16, 500, 128, 1><<<dim3(1, BSZ, NND), dim3(128), 0, stream>>>(
      h2, (long)BSZ * 4000, 4000, 500, w3, p3);
  stats_reduce<16, 256, 500><<<dim3(NND), dim3(256), 0, stream>>>(p3, g3, b3, scs3);
  conv_bn_pool_feat4<8, 16, 500, 128><<<dim3(1, BSZ, NND), dim3(128), 0, stream>>>(
      h2, (long)BSZ * 4000, 4000, 500, w3, scs3, feat);
  // graph tail
  graph_head<<<dim3(BSZ), dim3(256), 0, stream>>>(
      feat, gw1, gb1, gw2, gb2, gw3, gb3, fw1, fb1, fw2, fb2, (float*)d_out);
}